// Round 6
// baseline (652.921 us; speedup 1.0000x reference)
//
#include <hip/hip_runtime.h>
#include <hip/hip_bf16.h>

// UnifiedMambaBlock: B=2, L=1024, D_MODEL=2048, D_INNER=4096, N_STATE=16,
// DT_RANK=128, D_CONV=4.  ALL inputs/outputs fp32 (per reference dtypes).
// bf16 MFMA compute (no fp32 MFMA on CDNA4); fp32 epilogues.
//
// R5/R6: gemm_bt staging converted to async global->LDS (global_load_lds
// width=16, m97 2-barrier structure).  All GEMM operands pre-cast to bf16.
// R6 fixes the out_proj template arg (<0, float>, output is fp32).
//
// Pipeline:
//   0. cast u->u_bf, w_in->w_in_bf
//   1. build_wcat: concat w_xdt|w_xb|w_xc -> bf16 [256,4096]
//   2. gemm: xz[2048,8192](bf16) = u_bf @ w_in_bf^T + b_in
//   3. conv_silu: xc[2048,4096](bf16) from xz[:, :4096]   (overwrites u_bf)
//   4. gemm: proj[2048,256](bf16) = xc @ wcat^T
//   5. cast w_dt->w_dt_bf (wcat region, dead after 4)
//   6. gemm: dt[2048,4096](fp32) = softplus(proj[:,:128] @ w_dt_bf^T + b_dt)
//   7. scan: transposed-LDS + DPP reduce + chunk prefetch; yg in-place
//   8. cast w_out->w_out_bf (dtb region, dead after scan)
//   9. gemm: out[2048,2048](fp32) = yg @ w_out_bf^T + b_out

#define DEV __device__ __forceinline__

typedef __attribute__((ext_vector_type(8))) __bf16 bf16x8;
typedef __attribute__((ext_vector_type(4))) float f32x4;
typedef unsigned int u32;

DEV float bf2f(__hip_bfloat16 x) { return __bfloat162float(x); }
DEV __hip_bfloat16 f2bf(float x) { return __float2bfloat16(x); }
DEV float bfu2f(unsigned short u) {
    union { u32 i; float f; } c; c.i = ((u32)u) << 16; return c.f;
}
DEV unsigned short f2bfu(float x) {
    __hip_bfloat16 h = __float2bfloat16(x);
    return *reinterpret_cast<unsigned short*>(&h);
}
DEV float softplusf(float v) { return v > 20.f ? v : log1pf(__expf(v)); }
DEV float siluf(float v) { return v / (1.f + __expf(-v)); }

DEV void storeOut(float* C, size_t off, float v) { C[off] = v; }
DEV void storeOut(__hip_bfloat16* C, size_t off, float v) { C[off] = f2bf(v); }

// async 16B global -> LDS (one global_load_lds_dwordx4 per lane).
// LDS destination must be wave-uniform base + lane*16 (HW constraint).
DEV void async16(void* lds, const void* g) {
    __builtin_amdgcn_global_load_lds(
        (const __attribute__((address_space(1))) u32*)(unsigned long long)g,
        (__attribute__((address_space(3))) u32*)(u32)(unsigned long long)lds,
        16, 0, 0);
}

// DPP-based add of lane (permuted) value; reduction over 16-lane rows.
template <int CTRL>
DEV float dppadd(float v) {
    int x = __builtin_amdgcn_update_dpp(
        0, __builtin_bit_cast(int, v), CTRL, 0xF, 0xF, true);
    return v + __builtin_bit_cast(float, x);
}

// ---------------------------------------------------------------------------
// C = A @ W^T + bias GEMM, all-bf16 inputs, async LDS staging (m97 style).
// A:[M,K] bf16 (lda), W:[N,K] bf16 (ldw), C:[M,N] OutT (ldc), bias fp32.
// Block tile 128x128, BK=64, 256 threads = 4 waves 2x2, each wave 64x64 via
// 4x4 frags of mfma_f32_16x16x32_bf16.
// Requires: M%128==0, N%128==0, K%64==0, lda/ldw mult of 8 (16B alignment).
// ---------------------------------------------------------------------------
template <int ACT, typename OutT>
__global__ __launch_bounds__(256) void gemm_bt(
    const __hip_bfloat16* __restrict__ A, int lda,
    const __hip_bfloat16* __restrict__ W, int ldw,
    const float* __restrict__ bias,
    OutT* __restrict__ C, int ldc, int K)
{
    __shared__ __align__(16) unsigned short AsU[128 * 64];
    __shared__ __align__(16) unsigned short BsU[128 * 64];

    const int t     = threadIdx.x;
    const int mBase = blockIdx.y * 128;
    const int nBase = blockIdx.x * 128;
    const int wave  = t >> 6;
    const int lane  = t & 63;
    const int wm    = (wave >> 1) * 64;
    const int wn    = (wave & 1) * 64;
    const int ln15  = lane & 15;
    const int quad  = lane >> 4;

    f32x4 acc[4][4];
    const f32x4 vzero = {0.f, 0.f, 0.f, 0.f};
#pragma unroll
    for (int i = 0; i < 4; ++i)
#pragma unroll
        for (int j = 0; j < 4; ++j) acc[i][j] = vzero;

    for (int k0 = 0; k0 < K; k0 += 64) {
        __syncthreads();   // prev iteration's LDS reads complete
        // async global -> LDS: 4 chunks of A + 4 of B per thread.
        // chunk idx -> LDS offset idx*16B: within a wave this is
        // (i*256 + wave*64)*16 + lane*16 = uniform base + lane*16.  OK.
#pragma unroll
        for (int i = 0; i < 4; ++i) {
            int idx = i * 256 + t;
            int r = idx >> 3;
            int c = (idx & 7) << 3;
            async16(&AsU[idx * 8], A + (size_t)(mBase + r) * lda + k0 + c);
            async16(&BsU[idx * 8], W + (size_t)(nBase + r) * ldw + k0 + c);
        }
        __syncthreads();   // drains vmcnt -> tiles resident in LDS

#pragma unroll
        for (int kk = 0; kk < 64; kk += 32) {
            const int kof = kk + quad * 8;
            bf16x8 af[4], bfr[4];
#pragma unroll
            for (int i = 0; i < 4; ++i) {
                af[i]  = *reinterpret_cast<const bf16x8*>(&AsU[(wm + i * 16 + ln15) * 64 + kof]);
                bfr[i] = *reinterpret_cast<const bf16x8*>(&BsU[(wn + i * 16 + ln15) * 64 + kof]);
            }
#pragma unroll
            for (int i = 0; i < 4; ++i)
#pragma unroll
                for (int j = 0; j < 4; ++j)
                    acc[i][j] = __builtin_amdgcn_mfma_f32_16x16x32_bf16(af[i], bfr[j], acc[i][j], 0, 0, 0);
        }
    }

    // epilogue: C/D layout col = lane&15, row = quad*4 + reg
#pragma unroll
    for (int i = 0; i < 4; ++i) {
        const int gm = mBase + wm + i * 16 + quad * 4;
#pragma unroll
        for (int j = 0; j < 4; ++j) {
            const int gn = nBase + wn + j * 16 + ln15;
            const float bv = bias ? bias[gn] : 0.f;
#pragma unroll
            for (int r = 0; r < 4; ++r) {
                float v = acc[i][j][r] + bv;
                if (ACT == 1) v = softplusf(v);
                storeOut(C, (size_t)(gm + r) * ldc + gn, v);
            }
        }
    }
}

// ---------------------------------------------------------------------------
// fp32 -> bf16 cast, 8 elems/thread.  n must be a multiple of 2048.
// ---------------------------------------------------------------------------
__global__ __launch_bounds__(256) void cast_f32_bf16(
    const float* __restrict__ in, __hip_bfloat16* __restrict__ out)
{
    size_t i = ((size_t)blockIdx.x * 256 + threadIdx.x) * 8;
    const float4 a = *reinterpret_cast<const float4*>(in + i);
    const float4 b = *reinterpret_cast<const float4*>(in + i + 4);
    unsigned short r[8];
    r[0] = f2bfu(a.x); r[1] = f2bfu(a.y); r[2] = f2bfu(a.z); r[3] = f2bfu(a.w);
    r[4] = f2bfu(b.x); r[5] = f2bfu(b.y); r[6] = f2bfu(b.z); r[7] = f2bfu(b.w);
    *reinterpret_cast<uint4*>(out + i) = *reinterpret_cast<uint4*>(r);
}

// ---------------------------------------------------------------------------
// wcat bf16 [256,4096]: rows 0..127 w_xdt, 128..143 w_xb, 144..159 w_xc.
// ---------------------------------------------------------------------------
__global__ __launch_bounds__(256) void build_wcat(
    const float* __restrict__ w_xdt,
    const float* __restrict__ w_xb,
    const float* __restrict__ w_xc,
    __hip_bfloat16* __restrict__ wcat)
{
    int tid = blockIdx.x * 256 + threadIdx.x;
    int r = tid >> 12;
    int c = tid & 4095;
    float v = 0.f;
    if (r < 128)      v = w_xdt[r * 4096 + c];
    else if (r < 144) v = w_xb[(r - 128) * 4096 + c];
    else if (r < 160) v = w_xc[(r - 144) * 4096 + c];
    wcat[tid] = f2bf(v);
}

// ---------------------------------------------------------------------------
// causal depthwise conv (win 4, left pad 3) + bias + silu over xz[:, :4096]
// ---------------------------------------------------------------------------
__global__ __launch_bounds__(256) void conv_silu(
    const __hip_bfloat16* __restrict__ xz,
    const float* __restrict__ conv_w,
    const float* __restrict__ conv_b,
    __hip_bfloat16* __restrict__ xc)
{
    int tid = blockIdx.x * 256 + threadIdx.x;
    int d   = tid & 4095;
    int row = tid >> 12;
    int l   = row & 1023;
    float acc = conv_b[d];
#pragma unroll
    for (int k = 0; k < 4; ++k) {
        int ll = l - 3 + k;
        if (ll >= 0)
            acc += bf2f(xz[(size_t)(row - 3 + k) * 8192 + d]) * conv_w[d * 4 + k];
    }
    xc[tid] = f2bf(siluf(acc));
}

// ---------------------------------------------------------------------------
// selective scan (unchanged from R4): transposed LDS, DPP 16-lane reduction,
// register prefetch of the next time-chunk.  16 lanes/channel, 16 ch/block.
// ---------------------------------------------------------------------------
#define SCAN_T 128
#define ST4 132
#define ST2 136

__global__ __launch_bounds__(256) void scan_kernel(
    const float* __restrict__ dt,              // [2048, 4096] fp32
    __hip_bfloat16* xcyg,                      // [2048, 4096] bf16 in/out
    const __hip_bfloat16* __restrict__ proj,   // [2048, 256]; B at 128, C at 144
    const __hip_bfloat16* __restrict__ xz,     // [2048, 8192]; z at 4096+d
    const float* __restrict__ A_log,           // [4096, 16] fp32
    const float* __restrict__ Dp)              // [4096] fp32
{
    __shared__ __align__(16) float          s_dt[16 * ST4];
    __shared__ __align__(16) unsigned short s_x [16 * ST2];
    __shared__ __align__(16) unsigned short s_z [16 * ST2];
    __shared__ __align__(16) unsigned short s_B [16 * ST2];
    __shared__ __align__(16) unsigned short s_C [16 * ST2];
    __shared__ __align__(16) unsigned short s_y [16 * ST2];

    const int t   = threadIdx.x;
    const int g   = t >> 4;
    const int n   = t & 15;
    const int ch0 = blockIdx.x * 16;
    const int b   = ch0 >> 12;
    const int d0  = ch0 & 4095;
    const int d   = d0 + g;

    const float A2   = -__expf(A_log[d * 16 + n]) * 1.44269504f;
    const float Dpar = Dp[d];
    const size_t rowBase = (size_t)b * 1024;

    const int lrow = t >> 1;
    const int lh8  = (t & 1) << 3;
    const int dr0  = t >> 2,         dc0 = (t & 3) << 2;
    const int dr1  = (256 + t) >> 2, dc1 = ((256 + t) & 3) << 2;

    float4 rdt0, rdt1; uint4 rx, rz, rB, rC;
    auto load_chunk = [&](int t0) {
        rdt0 = *reinterpret_cast<const float4*>(&dt[(rowBase + t0 + dr0) * 4096 + d0 + dc0]);
        rdt1 = *reinterpret_cast<const float4*>(&dt[(rowBase + t0 + dr1) * 4096 + d0 + dc1]);
        rx = *reinterpret_cast<const uint4*>(&xcyg[(rowBase + t0 + lrow) * 4096 + d0 + lh8]);
        rz = *reinterpret_cast<const uint4*>(&xz[(rowBase + t0 + lrow) * 8192 + 4096 + d0 + lh8]);
        rB = *reinterpret_cast<const uint4*>(&proj[(rowBase + t0 + lrow) * 256 + 128 + lh8]);
        rC = *reinterpret_cast<const uint4*>(&proj[(rowBase + t0 + lrow) * 256 + 144 + lh8]);
    };

    load_chunk(0);
    float h = 0.f;

    for (int c = 0; c < 1024 / SCAN_T; ++c) {
        const int t0 = c * SCAN_T;
        __syncthreads();
        {
            const float* pd0 = (const float*)&rdt0;
            const float* pd1 = (const float*)&rdt1;
#pragma unroll
            for (int j = 0; j < 4; ++j) {
                s_dt[(dc0 + j) * ST4 + dr0] = pd0[j];
                s_dt[(dc1 + j) * ST4 + dr1] = pd1[j];
            }
            const unsigned short* px = (const unsigned short*)&rx;
            const unsigned short* pz = (const unsigned short*)&rz;
            const unsigned short* pB = (const unsigned short*)&rB;
            const unsigned short* pC = (const unsigned short*)&rC;
#pragma unroll
            for (int j = 0; j < 8; ++j) {
                s_x[(lh8 + j) * ST2 + lrow] = px[j];
                s_z[(lh8 + j) * ST2 + lrow] = pz[j];
                s_B[(lh8 + j) * ST2 + lrow] = pB[j];
                s_C[(lh8 + j) * ST2 + lrow] = pC[j];
            }
        }
        __syncthreads();
        if (c + 1 < 1024 / SCAN_T) load_chunk(t0 + SCAN_T);

#pragma unroll 1
        for (int l0 = 0; l0 < SCAN_T; l0 += 8) {
            const uint4 vx = *reinterpret_cast<const uint4*>(&s_x[g * ST2 + l0]);
            const uint4 vz = *reinterpret_cast<const uint4*>(&s_z[g * ST2 + l0]);
            const uint4 vB = *reinterpret_cast<const uint4*>(&s_B[n * ST2 + l0]);
            const uint4 vC = *reinterpret_cast<const uint4*>(&s_C[n * ST2 + l0]);
            const float4 vd0 = *reinterpret_cast<const float4*>(&s_dt[g * ST4 + l0]);
            const float4 vd1 = *reinterpret_cast<const float4*>(&s_dt[g * ST4 + l0 + 4]);
            const unsigned short* ux = (const unsigned short*)&vx;
            const unsigned short* uz = (const unsigned short*)&vz;
            const unsigned short* uB = (const unsigned short*)&vB;
            const unsigned short* uC = (const unsigned short*)&vC;
            const float* fd0 = (const float*)&vd0;
            const float* fd1 = (const float*)&vd1;
            unsigned short y8[8];
#pragma unroll
            for (int j = 0; j < 8; ++j) {
                const float dtv = (j < 4) ? fd0[j] : fd1[j - 4];
                const float xv  = bfu2f(ux[j]);
                const float Bn  = bfu2f(uB[j]);
                const float Cn  = bfu2f(uC[j]);
                const float e   = __builtin_amdgcn_exp2f(dtv * A2);
                h = fmaf(h, e, (xv * dtv) * Bn);
                float p = h * Cn;
                p = dppadd<0xB1>(p);
                p = dppadd<0x4E>(p);
                p = dppadd<0x141>(p);
                p = dppadd<0x140>(p);
                if (n == 0) {
                    const float zv  = bfu2f(uz[j]);
                    const float sig = __builtin_amdgcn_rcpf(
                        1.f + __builtin_amdgcn_exp2f(-zv * 1.44269504f));
                    y8[j] = f2bfu((p + Dpar * xv) * (zv * sig));
                }
            }
            if (n == 0)
                *reinterpret_cast<uint4*>(&s_y[g * ST2 + l0]) =
                    *reinterpret_cast<const uint4*>(y8);
        }
        __syncthreads();

        {
            unsigned short tmp[8];
#pragma unroll
            for (int j = 0; j < 8; ++j) tmp[j] = s_y[(lh8 + j) * ST2 + lrow];
            *reinterpret_cast<uint4*>(&xcyg[(rowBase + t0 + lrow) * 4096 + d0 + lh8]) =
                *reinterpret_cast<const uint4*>(tmp);
        }
    }
}

// ---------------------------------------------------------------------------
extern "C" void kernel_launch(void* const* d_in, const int* in_sizes, int n_in,
                              void* d_out, int out_size, void* d_ws, size_t ws_size,
                              hipStream_t stream)
{
    const float* u      = (const float*)d_in[0];
    const float* w_in   = (const float*)d_in[1];
    const float* b_in   = (const float*)d_in[2];
    const float* w_out  = (const float*)d_in[3];
    const float* b_out  = (const float*)d_in[4];
    const float* w_dt   = (const float*)d_in[5];
    const float* b_dt   = (const float*)d_in[6];
    const float* w_xdt  = (const float*)d_in[7];
    const float* w_xb   = (const float*)d_in[8];
    const float* w_xc   = (const float*)d_in[9];
    const float* conv_w = (const float*)d_in[10];
    const float* conv_b = (const float*)d_in[11];
    const float* A_log  = (const float*)d_in[12];
    const float* D_par  = (const float*)d_in[13];
    float* out = (float*)d_out;

    char* ws = (char*)d_ws;
    __hip_bfloat16* xz    = (__hip_bfloat16*)(ws);             // [2048,8192] 33.5 MB
    __hip_bfloat16* xc    = (__hip_bfloat16*)(ws + 33554432);  // [2048,4096] 16.8 MB
    __hip_bfloat16* u_bf  = (__hip_bfloat16*)(ws + 33554432);  // dead before xc written
    __hip_bfloat16* wcat  = (__hip_bfloat16*)(ws + 50331648);  // [256,4096]  2.1 MB
    __hip_bfloat16* w_dt_bf = (__hip_bfloat16*)(ws + 50331648);// [4096,128] 1 MB (after wcat dead)
    __hip_bfloat16* proj  = (__hip_bfloat16*)(ws + 52428800);  // [2048,256]  1.0 MB
    float*          dtb   = (float*)(ws + 53477376);           // [2048,4096] 33.5 MB
    __hip_bfloat16* w_in_bf  = (__hip_bfloat16*)(ws + 53477376); // dead before dtb written
    __hip_bfloat16* w_out_bf = (__hip_bfloat16*)(ws + 53477376); // after scan (dtb dead)
    // total 87.0 MB

    // 0. pre-cast to bf16
    cast_f32_bf16<<<2048, 256, 0, stream>>>(u, u_bf);
    cast_f32_bf16<<<8192, 256, 0, stream>>>(w_in, w_in_bf);

    // 1. weight concat
    build_wcat<<<4096, 256, 0, stream>>>(w_xdt, w_xb, w_xc, wcat);

    // 2. in_proj: xz = u @ w_in^T + b_in     (M=2048, N=8192, K=2048)
    gemm_bt<0, __hip_bfloat16><<<dim3(64, 16), 256, 0, stream>>>(
        u_bf, 2048, w_in_bf, 2048, b_in, xz, 8192, 2048);

    // 3. conv + silu (overwrites u_bf region with xc)
    conv_silu<<<32768, 256, 0, stream>>>(xz, conv_w, conv_b, xc);

    // 4. proj = xc @ wcat^T                  (M=2048, N=256, K=4096)
    gemm_bt<0, __hip_bfloat16><<<dim3(2, 16), 256, 0, stream>>>(
        xc, 4096, wcat, 4096, (const float*)nullptr, proj, 256, 4096);

    // 5. cast w_dt (wcat region dead now)
    cast_f32_bf16<<<256, 256, 0, stream>>>(w_dt, w_dt_bf);

    // 6. dt = softplus(proj[:, :128] @ w_dt^T + b_dt)  (M=2048, N=4096, K=128)
    gemm_bt<1, float><<<dim3(32, 16), 256, 0, stream>>>(
        proj, 256, w_dt_bf, 128, b_dt, dtb, 4096, 128);

    // 7. selective scan -> yg (in-place over xc)
    scan_kernel<<<512, 256, 0, stream>>>(dtb, xc, proj, xz, A_log, D_par);

    // 8. cast w_out (dtb region dead now)
    cast_f32_bf16<<<4096, 256, 0, stream>>>(w_out, w_out_bf);

    // 9. out = yg @ w_out^T + b_out          (M=2048, N=2048, K=4096)
    gemm_bt<0, float><<<dim3(16, 16), 256, 0, stream>>>(
        xc, 4096, w_out_bf, 4096, b_out, out, 2048, 4096);
}

// Round 7
// 547.206 us; speedup vs baseline: 1.1932x; 1.1932x over previous
//
#include <hip/hip_runtime.h>
#include <hip/hip_bf16.h>

// UnifiedMambaBlock: B=2, L=1024, D_MODEL=2048, D_INNER=4096, N_STATE=16,
// DT_RANK=128, D_CONV=4.  ALL inputs/outputs fp32 (per reference dtypes).
// bf16 MFMA compute (no fp32 MFMA on CDNA4); fp32 epilogues.
//
// R7: GEMMs double-buffered (async global_load_lds prefetch of tile k+1 in
// flight during compute of tile k) to hide load latency at 1-2 blocks/CU.
// proj GEMM split-K (8 slices, fp32 partials + reduce) -- was 32 blocks.
//
// Pipeline:
//   0. cast u->u_bf, w_in->w_in_bf
//   1. build_wcat: concat w_xdt|w_xb|w_xc -> bf16 [256,4096]
//   2. gemm: xz[2048,8192](bf16) = u_bf @ w_in_bf^T + b_in
//   3. conv_silu: xc[2048,4096](bf16) from xz[:, :4096]
//   4. gemm_sk + reduce: proj[2048,256](bf16) = xc @ wcat^T
//   5. cast w_dt->w_dt_bf
//   6. gemm: dt[2048,4096](fp32) = softplus(proj[:,:128] @ w_dt_bf^T + b_dt)
//   7. scan: transposed-LDS + DPP reduce + chunk prefetch; yg in-place
//   8. cast w_out->w_out_bf
//   9. gemm: out[2048,2048](fp32) = yg @ w_out_bf^T + b_out

#define DEV __device__ __forceinline__

typedef __attribute__((ext_vector_type(8))) __bf16 bf16x8;
typedef __attribute__((ext_vector_type(4))) float f32x4;
typedef unsigned int u32;

DEV float bf2f(__hip_bfloat16 x) { return __bfloat162float(x); }
DEV __hip_bfloat16 f2bf(float x) { return __float2bfloat16(x); }
DEV float bfu2f(unsigned short u) {
    union { u32 i; float f; } c; c.i = ((u32)u) << 16; return c.f;
}
DEV unsigned short f2bfu(float x) {
    __hip_bfloat16 h = __float2bfloat16(x);
    return *reinterpret_cast<unsigned short*>(&h);
}
DEV float softplusf(float v) { return v > 20.f ? v : log1pf(__expf(v)); }
DEV float siluf(float v) { return v / (1.f + __expf(-v)); }

DEV void storeOut(float* C, size_t off, float v) { C[off] = v; }
DEV void storeOut(__hip_bfloat16* C, size_t off, float v) { C[off] = f2bf(v); }

// async 16B global -> LDS (global_load_lds_dwordx4).
// LDS destination must be wave-uniform base + lane*16 (HW constraint).
DEV void async16(void* lds, const void* g) {
    __builtin_amdgcn_global_load_lds(
        (const __attribute__((address_space(1))) u32*)(unsigned long long)g,
        (__attribute__((address_space(3))) u32*)(u32)(unsigned long long)lds,
        16, 0, 0);
}

// DPP-based add of lane (permuted) value; reduction over 16-lane rows.
template <int CTRL>
DEV float dppadd(float v) {
    int x = __builtin_amdgcn_update_dpp(
        0, __builtin_bit_cast(int, v), CTRL, 0xF, 0xF, true);
    return v + __builtin_bit_cast(float, x);
}

// ---------------------------------------------------------------------------
// C = A @ W^T + bias GEMM, bf16 inputs, DOUBLE-BUFFERED async LDS staging.
// Block tile 128x128, BK=64, 256 threads = 4 waves 2x2, wave does 64x64 via
// 4x4 frags of mfma_f32_16x16x32_bf16.  Tile k+1's global_load_lds is in
// flight while tile k computes; the next barrier pays only residual latency.
// Requires: M%128==0, N%128==0, K%64==0, lda/ldw mult of 8.
// ---------------------------------------------------------------------------
template <int ACT, typename OutT>
__global__ __launch_bounds__(256) void gemm_bt(
    const __hip_bfloat16* __restrict__ A, int lda,
    const __hip_bfloat16* __restrict__ W, int ldw,
    const float* __restrict__ bias,
    OutT* __restrict__ C, int ldc, int K)
{
    __shared__ __align__(16) unsigned short AsU[2][128 * 64];
    __shared__ __align__(16) unsigned short BsU[2][128 * 64];

    const int t     = threadIdx.x;
    const int mBase = blockIdx.y * 128;
    const int nBase = blockIdx.x * 128;
    const int wave  = t >> 6;
    const int lane  = t & 63;
    const int wm    = (wave >> 1) * 64;
    const int wn    = (wave & 1) * 64;
    const int ln15  = lane & 15;
    const int quad  = lane >> 4;

    f32x4 acc[4][4];
    const f32x4 vzero = {0.f, 0.f, 0.f, 0.f};
#pragma unroll
    for (int i = 0; i < 4; ++i)
#pragma unroll
        for (int j = 0; j < 4; ++j) acc[i][j] = vzero;

    // stage tile at k0 into buffer buf
    auto stage = [&](int buf, int k0) {
#pragma unroll
        for (int i = 0; i < 4; ++i) {
            int idx = i * 256 + t;
            int r = idx >> 3;
            int c = (idx & 7) << 3;
            async16(&AsU[buf][idx * 8], A + (size_t)(mBase + r) * lda + k0 + c);
            async16(&BsU[buf][idx * 8], W + (size_t)(nBase + r) * ldw + k0 + c);
        }
    };

    const int nIter = K >> 6;
    stage(0, 0);

    for (int it = 0; it < nIter; ++it) {
        __syncthreads();   // buf[it&1] resident; prior reads of other buf done
        if (it + 1 < nIter) stage((it + 1) & 1, (it + 1) << 6);
        const unsigned short* As = AsU[it & 1];
        const unsigned short* Bs = BsU[it & 1];

#pragma unroll
        for (int kk = 0; kk < 64; kk += 32) {
            const int kof = kk + quad * 8;
            bf16x8 af[4], bfr[4];
#pragma unroll
            for (int i = 0; i < 4; ++i) {
                af[i]  = *reinterpret_cast<const bf16x8*>(&As[(wm + i * 16 + ln15) * 64 + kof]);
                bfr[i] = *reinterpret_cast<const bf16x8*>(&Bs[(wn + i * 16 + ln15) * 64 + kof]);
            }
#pragma unroll
            for (int i = 0; i < 4; ++i)
#pragma unroll
                for (int j = 0; j < 4; ++j)
                    acc[i][j] = __builtin_amdgcn_mfma_f32_16x16x32_bf16(af[i], bfr[j], acc[i][j], 0, 0, 0);
        }
    }

    // epilogue: C/D layout col = lane&15, row = quad*4 + reg
#pragma unroll
    for (int i = 0; i < 4; ++i) {
        const int gm = mBase + wm + i * 16 + quad * 4;
#pragma unroll
        for (int j = 0; j < 4; ++j) {
            const int gn = nBase + wn + j * 16 + ln15;
            const float bv = bias ? bias[gn] : 0.f;
#pragma unroll
            for (int r = 0; r < 4; ++r) {
                float v = acc[i][j][r] + bv;
                if (ACT == 1) v = softplusf(v);
                storeOut(C, (size_t)(gm + r) * ldc + gn, v);
            }
        }
    }
}

// ---------------------------------------------------------------------------
// Split-K variant: grid (nx, ny, SLICES); slice z handles K-range
// [z*K/SLICES, (z+1)*K/SLICES), stores fp32 partial at part + z*sliceElems.
// ---------------------------------------------------------------------------
__global__ __launch_bounds__(256) void gemm_bt_sk(
    const __hip_bfloat16* __restrict__ A, int lda,
    const __hip_bfloat16* __restrict__ W, int ldw,
    float* __restrict__ part, int ldc, int K, int slices, int sliceElems)
{
    __shared__ __align__(16) unsigned short AsU[2][128 * 64];
    __shared__ __align__(16) unsigned short BsU[2][128 * 64];

    const int t     = threadIdx.x;
    const int mBase = blockIdx.y * 128;
    const int nBase = blockIdx.x * 128;
    const int kLen  = K / slices;
    const int kOff  = blockIdx.z * kLen;
    const int wave  = t >> 6;
    const int lane  = t & 63;
    const int wm    = (wave >> 1) * 64;
    const int wn    = (wave & 1) * 64;
    const int ln15  = lane & 15;
    const int quad  = lane >> 4;

    f32x4 acc[4][4];
    const f32x4 vzero = {0.f, 0.f, 0.f, 0.f};
#pragma unroll
    for (int i = 0; i < 4; ++i)
#pragma unroll
        for (int j = 0; j < 4; ++j) acc[i][j] = vzero;

    auto stage = [&](int buf, int k0) {
#pragma unroll
        for (int i = 0; i < 4; ++i) {
            int idx = i * 256 + t;
            int r = idx >> 3;
            int c = (idx & 7) << 3;
            async16(&AsU[buf][idx * 8], A + (size_t)(mBase + r) * lda + k0 + c);
            async16(&BsU[buf][idx * 8], W + (size_t)(nBase + r) * ldw + k0 + c);
        }
    };

    const int nIter = kLen >> 6;
    stage(0, kOff);

    for (int it = 0; it < nIter; ++it) {
        __syncthreads();
        if (it + 1 < nIter) stage((it + 1) & 1, kOff + ((it + 1) << 6));
        const unsigned short* As = AsU[it & 1];
        const unsigned short* Bs = BsU[it & 1];

#pragma unroll
        for (int kk = 0; kk < 64; kk += 32) {
            const int kof = kk + quad * 8;
            bf16x8 af[4], bfr[4];
#pragma unroll
            for (int i = 0; i < 4; ++i) {
                af[i]  = *reinterpret_cast<const bf16x8*>(&As[(wm + i * 16 + ln15) * 64 + kof]);
                bfr[i] = *reinterpret_cast<const bf16x8*>(&Bs[(wn + i * 16 + ln15) * 64 + kof]);
            }
#pragma unroll
            for (int i = 0; i < 4; ++i)
#pragma unroll
                for (int j = 0; j < 4; ++j)
                    acc[i][j] = __builtin_amdgcn_mfma_f32_16x16x32_bf16(af[i], bfr[j], acc[i][j], 0, 0, 0);
        }
    }

    float* Cp = part + (size_t)blockIdx.z * sliceElems;
#pragma unroll
    for (int i = 0; i < 4; ++i) {
        const int gm = mBase + wm + i * 16 + quad * 4;
#pragma unroll
        for (int j = 0; j < 4; ++j) {
            const int gn = nBase + wn + j * 16 + ln15;
#pragma unroll
            for (int r = 0; r < 4; ++r)
                Cp[(size_t)(gm + r) * ldc + gn] = acc[i][j][r];
        }
    }
}

// sum 8 fp32 partials -> bf16 proj.  total = 2048*256 elems.
__global__ __launch_bounds__(256) void reduce_proj(
    const float* __restrict__ part, __hip_bfloat16* __restrict__ proj)
{
    int i = blockIdx.x * 256 + threadIdx.x;
    float s = 0.f;
#pragma unroll
    for (int z = 0; z < 8; ++z) s += part[(size_t)z * 524288 + i];
    proj[i] = f2bf(s);
}

// ---------------------------------------------------------------------------
// fp32 -> bf16 cast, 8 elems/thread.  n must be a multiple of 2048.
// ---------------------------------------------------------------------------
__global__ __launch_bounds__(256) void cast_f32_bf16(
    const float* __restrict__ in, __hip_bfloat16* __restrict__ out)
{
    size_t i = ((size_t)blockIdx.x * 256 + threadIdx.x) * 8;
    const float4 a = *reinterpret_cast<const float4*>(in + i);
    const float4 b = *reinterpret_cast<const float4*>(in + i + 4);
    unsigned short r[8];
    r[0] = f2bfu(a.x); r[1] = f2bfu(a.y); r[2] = f2bfu(a.z); r[3] = f2bfu(a.w);
    r[4] = f2bfu(b.x); r[5] = f2bfu(b.y); r[6] = f2bfu(b.z); r[7] = f2bfu(b.w);
    *reinterpret_cast<uint4*>(out + i) = *reinterpret_cast<uint4*>(r);
}

// ---------------------------------------------------------------------------
// wcat bf16 [256,4096]: rows 0..127 w_xdt, 128..143 w_xb, 144..159 w_xc.
// ---------------------------------------------------------------------------
__global__ __launch_bounds__(256) void build_wcat(
    const float* __restrict__ w_xdt,
    const float* __restrict__ w_xb,
    const float* __restrict__ w_xc,
    __hip_bfloat16* __restrict__ wcat)
{
    int tid = blockIdx.x * 256 + threadIdx.x;
    int r = tid >> 12;
    int c = tid & 4095;
    float v = 0.f;
    if (r < 128)      v = w_xdt[r * 4096 + c];
    else if (r < 144) v = w_xb[(r - 128) * 4096 + c];
    else if (r < 160) v = w_xc[(r - 144) * 4096 + c];
    wcat[tid] = f2bf(v);
}

// ---------------------------------------------------------------------------
// causal depthwise conv (win 4, left pad 3) + bias + silu over xz[:, :4096]
// ---------------------------------------------------------------------------
__global__ __launch_bounds__(256) void conv_silu(
    const __hip_bfloat16* __restrict__ xz,
    const float* __restrict__ conv_w,
    const float* __restrict__ conv_b,
    __hip_bfloat16* __restrict__ xc)
{
    int tid = blockIdx.x * 256 + threadIdx.x;
    int d   = tid & 4095;
    int row = tid >> 12;
    int l   = row & 1023;
    float acc = conv_b[d];
#pragma unroll
    for (int k = 0; k < 4; ++k) {
        int ll = l - 3 + k;
        if (ll >= 0)
            acc += bf2f(xz[(size_t)(row - 3 + k) * 8192 + d]) * conv_w[d * 4 + k];
    }
    xc[tid] = f2bf(siluf(acc));
}

// ---------------------------------------------------------------------------
// selective scan (unchanged from R4): transposed LDS, DPP 16-lane reduction,
// register prefetch of the next time-chunk.  16 lanes/channel, 16 ch/block.
// ---------------------------------------------------------------------------
#define SCAN_T 128
#define ST4 132
#define ST2 136

__global__ __launch_bounds__(256) void scan_kernel(
    const float* __restrict__ dt,              // [2048, 4096] fp32
    __hip_bfloat16* xcyg,                      // [2048, 4096] bf16 in/out
    const __hip_bfloat16* __restrict__ proj,   // [2048, 256]; B at 128, C at 144
    const __hip_bfloat16* __restrict__ xz,     // [2048, 8192]; z at 4096+d
    const float* __restrict__ A_log,           // [4096, 16] fp32
    const float* __restrict__ Dp)              // [4096] fp32
{
    __shared__ __align__(16) float          s_dt[16 * ST4];
    __shared__ __align__(16) unsigned short s_x [16 * ST2];
    __shared__ __align__(16) unsigned short s_z [16 * ST2];
    __shared__ __align__(16) unsigned short s_B [16 * ST2];
    __shared__ __align__(16) unsigned short s_C [16 * ST2];
    __shared__ __align__(16) unsigned short s_y [16 * ST2];

    const int t   = threadIdx.x;
    const int g   = t >> 4;
    const int n   = t & 15;
    const int ch0 = blockIdx.x * 16;
    const int b   = ch0 >> 12;
    const int d0  = ch0 & 4095;
    const int d   = d0 + g;

    const float A2   = -__expf(A_log[d * 16 + n]) * 1.44269504f;
    const float Dpar = Dp[d];
    const size_t rowBase = (size_t)b * 1024;

    const int lrow = t >> 1;
    const int lh8  = (t & 1) << 3;
    const int dr0  = t >> 2,         dc0 = (t & 3) << 2;
    const int dr1  = (256 + t) >> 2, dc1 = ((256 + t) & 3) << 2;

    float4 rdt0, rdt1; uint4 rx, rz, rB, rC;
    auto load_chunk = [&](int t0) {
        rdt0 = *reinterpret_cast<const float4*>(&dt[(rowBase + t0 + dr0) * 4096 + d0 + dc0]);
        rdt1 = *reinterpret_cast<const float4*>(&dt[(rowBase + t0 + dr1) * 4096 + d0 + dc1]);
        rx = *reinterpret_cast<const uint4*>(&xcyg[(rowBase + t0 + lrow) * 4096 + d0 + lh8]);
        rz = *reinterpret_cast<const uint4*>(&xz[(rowBase + t0 + lrow) * 8192 + 4096 + d0 + lh8]);
        rB = *reinterpret_cast<const uint4*>(&proj[(rowBase + t0 + lrow) * 256 + 128 + lh8]);
        rC = *reinterpret_cast<const uint4*>(&proj[(rowBase + t0 + lrow) * 256 + 144 + lh8]);
    };

    load_chunk(0);
    float h = 0.f;

    for (int c = 0; c < 1024 / SCAN_T; ++c) {
        const int t0 = c * SCAN_T;
        __syncthreads();
        {
            const float* pd0 = (const float*)&rdt0;
            const float* pd1 = (const float*)&rdt1;
#pragma unroll
            for (int j = 0; j < 4; ++j) {
                s_dt[(dc0 + j) * ST4 + dr0] = pd0[j];
                s_dt[(dc1 + j) * ST4 + dr1] = pd1[j];
            }
            const unsigned short* px = (const unsigned short*)&rx;
            const unsigned short* pz = (const unsigned short*)&rz;
            const unsigned short* pB = (const unsigned short*)&rB;
            const unsigned short* pC = (const unsigned short*)&rC;
#pragma unroll
            for (int j = 0; j < 8; ++j) {
                s_x[(lh8 + j) * ST2 + lrow] = px[j];
                s_z[(lh8 + j) * ST2 + lrow] = pz[j];
                s_B[(lh8 + j) * ST2 + lrow] = pB[j];
                s_C[(lh8 + j) * ST2 + lrow] = pC[j];
            }
        }
        __syncthreads();
        if (c + 1 < 1024 / SCAN_T) load_chunk(t0 + SCAN_T);

#pragma unroll 1
        for (int l0 = 0; l0 < SCAN_T; l0 += 8) {
            const uint4 vx = *reinterpret_cast<const uint4*>(&s_x[g * ST2 + l0]);
            const uint4 vz = *reinterpret_cast<const uint4*>(&s_z[g * ST2 + l0]);
            const uint4 vB = *reinterpret_cast<const uint4*>(&s_B[n * ST2 + l0]);
            const uint4 vC = *reinterpret_cast<const uint4*>(&s_C[n * ST2 + l0]);
            const float4 vd0 = *reinterpret_cast<const float4*>(&s_dt[g * ST4 + l0]);
            const float4 vd1 = *reinterpret_cast<const float4*>(&s_dt[g * ST4 + l0 + 4]);
            const unsigned short* ux = (const unsigned short*)&vx;
            const unsigned short* uz = (const unsigned short*)&vz;
            const unsigned short* uB = (const unsigned short*)&vB;
            const unsigned short* uC = (const unsigned short*)&vC;
            const float* fd0 = (const float*)&vd0;
            const float* fd1 = (const float*)&vd1;
            unsigned short y8[8];
#pragma unroll
            for (int j = 0; j < 8; ++j) {
                const float dtv = (j < 4) ? fd0[j] : fd1[j - 4];
                const float xv  = bfu2f(ux[j]);
                const float Bn  = bfu2f(uB[j]);
                const float Cn  = bfu2f(uC[j]);
                const float e   = __builtin_amdgcn_exp2f(dtv * A2);
                h = fmaf(h, e, (xv * dtv) * Bn);
                float p = h * Cn;
                p = dppadd<0xB1>(p);
                p = dppadd<0x4E>(p);
                p = dppadd<0x141>(p);
                p = dppadd<0x140>(p);
                if (n == 0) {
                    const float zv  = bfu2f(uz[j]);
                    const float sig = __builtin_amdgcn_rcpf(
                        1.f + __builtin_amdgcn_exp2f(-zv * 1.44269504f));
                    y8[j] = f2bfu((p + Dpar * xv) * (zv * sig));
                }
            }
            if (n == 0)
                *reinterpret_cast<uint4*>(&s_y[g * ST2 + l0]) =
                    *reinterpret_cast<const uint4*>(y8);
        }
        __syncthreads();

        {
            unsigned short tmp[8];
#pragma unroll
            for (int j = 0; j < 8; ++j) tmp[j] = s_y[(lh8 + j) * ST2 + lrow];
            *reinterpret_cast<uint4*>(&xcyg[(rowBase + t0 + lrow) * 4096 + d0 + lh8]) =
                *reinterpret_cast<const uint4*>(tmp);
        }
    }
}

// ---------------------------------------------------------------------------
extern "C" void kernel_launch(void* const* d_in, const int* in_sizes, int n_in,
                              void* d_out, int out_size, void* d_ws, size_t ws_size,
                              hipStream_t stream)
{
    const float* u      = (const float*)d_in[0];
    const float* w_in   = (const float*)d_in[1];
    const float* b_in   = (const float*)d_in[2];
    const float* w_out  = (const float*)d_in[3];
    const float* b_out  = (const float*)d_in[4];
    const float* w_dt   = (const float*)d_in[5];
    const float* b_dt   = (const float*)d_in[6];
    const float* w_xdt  = (const float*)d_in[7];
    const float* w_xb   = (const float*)d_in[8];
    const float* w_xc   = (const float*)d_in[9];
    const float* conv_w = (const float*)d_in[10];
    const float* conv_b = (const float*)d_in[11];
    const float* A_log  = (const float*)d_in[12];
    const float* D_par  = (const float*)d_in[13];
    float* out = (float*)d_out;

    char* ws = (char*)d_ws;
    __hip_bfloat16* xz    = (__hip_bfloat16*)(ws);             // [2048,8192] 33.5 MB
    __hip_bfloat16* xc    = (__hip_bfloat16*)(ws + 33554432);  // [2048,4096] 16.8 MB
    __hip_bfloat16* u_bf  = (__hip_bfloat16*)(ws + 33554432);  // dead before xc written
    __hip_bfloat16* wcat  = (__hip_bfloat16*)(ws + 50331648);  // [256,4096]  2.1 MB
    __hip_bfloat16* w_dt_bf = (__hip_bfloat16*)(ws + 50331648);// [4096,128] 1 MB (after wcat dead)
    __hip_bfloat16* proj  = (__hip_bfloat16*)(ws + 52428800);  // [2048,256]  1.0 MB
    float*          dtb   = (float*)(ws + 53477376);           // [2048,4096] 33.5 MB
    __hip_bfloat16* w_in_bf  = (__hip_bfloat16*)(ws + 53477376); // dead before dtb written
    float*          projPart = (float*)(ws + 53477376);         // [8,2048,256] 16.8 MB (pre-dtb)
    __hip_bfloat16* w_out_bf = (__hip_bfloat16*)(ws + 53477376); // after scan (dtb dead)
    // total 87.0 MB

    // 0. pre-cast to bf16
    cast_f32_bf16<<<2048, 256, 0, stream>>>(u, u_bf);
    cast_f32_bf16<<<8192, 256, 0, stream>>>(w_in, w_in_bf);

    // 1. weight concat
    build_wcat<<<4096, 256, 0, stream>>>(w_xdt, w_xb, w_xc, wcat);

    // 2. in_proj: xz = u @ w_in^T + b_in     (M=2048, N=8192, K=2048)
    gemm_bt<0, __hip_bfloat16><<<dim3(64, 16), 256, 0, stream>>>(
        u_bf, 2048, w_in_bf, 2048, b_in, xz, 8192, 2048);

    // 3. conv + silu (overwrites u_bf region with xc; w_in_bf dead after 2)
    conv_silu<<<32768, 256, 0, stream>>>(xz, conv_w, conv_b, xc);

    // 4. proj = xc @ wcat^T, split-K=8      (M=2048, N=256, K=4096)
    gemm_bt_sk<<<dim3(2, 16, 8), 256, 0, stream>>>(
        xc, 4096, wcat, 4096, projPart, 256, 4096, 8, 524288);
    reduce_proj<<<2048, 256, 0, stream>>>(projPart, proj);

    // 5. cast w_dt (wcat region dead now)
    cast_f32_bf16<<<256, 256, 0, stream>>>(w_dt, w_dt_bf);

    // 6. dt = softplus(proj[:, :128] @ w_dt^T + b_dt)  (M=2048, N=4096, K=128)
    gemm_bt<1, float><<<dim3(32, 16), 256, 0, stream>>>(
        proj, 256, w_dt_bf, 128, b_dt, dtb, 4096, 128);

    // 7. selective scan -> yg (in-place over xc)
    scan_kernel<<<512, 256, 0, stream>>>(dtb, xc, proj, xz, A_log, D_par);

    // 8. cast w_out (dtb region dead now)
    cast_f32_bf16<<<4096, 256, 0, stream>>>(w_out, w_out_bf);

    // 9. out = yg @ w_out^T + b_out          (M=2048, N=2048, K=4096)
    gemm_bt<0, float><<<dim3(16, 16), 256, 0, stream>>>(
        xc, 4096, w_out_bf, 4096, b_out, out, 2048, 4096);
}